// Round 1
// baseline (7054.224 us; speedup 1.0000x reference)
//
#include <hip/hip_runtime.h>

// SPINN stack-encoder, persistent cooperative kernel, fp32.
// 256 WGs x 256 threads, 1 WG/CU (117KB LDS). 2 grid barriers per step.
// Tree matmul: 64 col-tiles(32 cols) x 4 K-slices(256) -> hpre4 partials.
// Tracking matmul: 8 b-tiles(16) x 32 c-tiles(8), K=1600.
// Phase B: tracking elementwise -> th2 (LDS), x@W (K=64) + gate fusion,
// stack row write, output at step 63.

constexpr int NB  = 128;
constexpr int LL  = 32;
constexpr int HH  = 512;
constexpr int XD  = 64;
constexpr int TT  = 63;
constexpr int D2  = 1024;
constexpr int NWG = 256;
constexpr int NTH = 256;
constexpr int SROWS = 64;            // stack rows per batch (TT+1)

struct Params {
  const float* seq; const int* trans;
  const float* Wx[4];                // gate order i,o,f,u ; Wx[2]==W_o (ref bug kept)
  const float* Ul[4]; const float* Ur[4];
  const float* bias[4];              // b_i, b_o, b_f, b_u
  const float* tWih; const float* tWhh; const float* tbih; const float* tbhh;
  const float* th0; const float* tc0;
  float* stack; float* hpre4; float* tg;
  float* thb[2]; float* tcb[2];
  unsigned* cnt; unsigned* bar;
  float* out;
};

__device__ __forceinline__ float sigm(float x) { return 1.0f / (1.0f + __expf(-x)); }

__device__ __forceinline__ void gsync(unsigned* cnt, unsigned* bar, unsigned gen) {
  __syncthreads();
  if (threadIdx.x == 0) {
    __threadfence();  // release all prior global writes (agent scope)
    unsigned arrived = __hip_atomic_fetch_add(cnt, 1u, __ATOMIC_ACQ_REL,
                                              __HIP_MEMORY_SCOPE_AGENT) + 1u;
    if (arrived == (unsigned)NWG) {
      __hip_atomic_store(cnt, 0u, __ATOMIC_RELAXED, __HIP_MEMORY_SCOPE_AGENT);
      __hip_atomic_store(bar, gen, __ATOMIC_RELEASE, __HIP_MEMORY_SCOPE_AGENT);
    } else {
      while (__hip_atomic_load(bar, __ATOMIC_ACQUIRE, __HIP_MEMORY_SCOPE_AGENT) < gen) {
        __builtin_amdgcn_s_sleep(2);
      }
    }
    __threadfence();  // acquire
  }
  __syncthreads();
}

__launch_bounds__(NTH)
__global__ void spinn_kernel(Params p) {
  const int w = blockIdx.x;
  const int t = threadIdx.x;

  __shared__ float wTree[32][260];        // this WG's U slice: 32 cols x 256 K
  __shared__ float wTrack[8][1604];       // this WG's tW slice: 8 cols x 1600 K
  __shared__ float scratch[128][36];      // operand chunk staging / tin / th2s
  __shared__ float wXs[4][4][68];         // W_g rows for phase-B n-tile
  __shared__ float biasS[4][4];
  __shared__ unsigned char qstk[NB][64];
  __shared__ short qln[NB];
  __shared__ short bpt[NB];
  __shared__ unsigned char sp1s[NB], sp2s[NB], reds[NB], bufs[NB];
  __shared__ float tpart[128];
  __shared__ int anyred;

  // role decode
  const int ks = w & 3;           // tree K-slice: 0,1=h_l(sp1), 2,3=h_r(sp2)
  const int ct = w >> 2;          // tree col tile 0..63
  const int g  = ct >> 4;         // gate 0..3 (i,o,f,u)
  const int n0 = (ct & 15) * 32;  // n base within gate
  const int tb = w >> 5;          // tracking b-tile 0..7
  const int tcid = w & 31;        // tracking c-tile 0..31
  const int bh = w >> 7;          // phase-B b-half
  const int b0B = bh * 64;
  const int n0B = (w & 127) * 4;  // phase-B n tile

  // ---- prologue: LDS weight loads (stationary across all 63 steps)
  {
    const float* U = (ks < 2) ? p.Ul[g] : p.Ur[g];
    const int koff = (ks & 1) * 256;
    for (int i = t; i < 32 * 256; i += NTH) {
      int c = i >> 8, kk = i & 255;
      wTree[c][kk] = U[(size_t)(n0 + c) * HH + koff + kk];
    }
    for (int i = t; i < 8 * 1600; i += NTH) {
      int c = i / 1600, kk = i - c * 1600;
      int ca = tcid * 8 + c;
      wTrack[c][kk] = (kk < 1536) ? p.tWih[(size_t)ca * 1536 + kk]
                                  : p.tWhh[(size_t)ca * 64 + (kk - 1536)];
    }
    for (int i = t; i < 4 * 4 * 64; i += NTH) {
      int g2 = i >> 8, r = i & 255; int ni = r >> 6, j = r & 63;
      wXs[g2][ni][j] = p.Wx[g2][(size_t)(n0B + ni) * 64 + j];
    }
    if (t < 16) biasS[t >> 2][t & 3] = p.bias[t >> 2][n0B + (t & 3)];
  }
  // zero stack row 0 (read when queue empty) + init tracking state
  for (int i = w * NTH + t; i < NB * D2; i += NWG * NTH) {
    p.stack[(size_t)(i >> 10) * (SROWS * D2) + (i & 1023)] = 0.0f;
  }
  if (w == 0) {
    for (int i = t; i < NB * XD; i += NTH) { p.thb[0][i] = p.th0[i]; p.tcb[0][i] = p.tc0[i]; }
  }
  if (t < NB) { qln[t] = 0; bpt[t] = 0; }
  __syncthreads();
  unsigned gen = 0;
  gsync(p.cnt, p.bar, ++gen);

  for (int step = 1; step <= TT; ++step) {
    const int cur = (step - 1) & 1, nxt = step & 1;

    // ---- per-WG redundant shift/reduce schedule sim (LDS-local)
    if (t < NB) {
      int b = t;
      int mask = p.trans[b * TT + (step - 1)];
      int qn = qln[b];
      int s1 = (qn >= 1) ? qstk[b][qn - 1] : 0;
      int s2 = (qn >= 2) ? qstk[b][qn - 2] : 0;
      int rd = (mask == 1);
      sp1s[b] = (unsigned char)s1;
      sp2s[b] = (unsigned char)s2;
      reds[b] = (unsigned char)rd;
      int bp = bpt[b];
      bufs[b] = (unsigned char)((bp < LL) ? bp : LL);
      int qn2 = rd ? (qn - 2) : qn;
      qstk[b][qn2] = (unsigned char)step;
      qln[b] = (short)(qn2 + 1);
      bpt[b] = (short)(bp + (rd ? 0 : 1));
    }
    __syncthreads();
    if (t == 0) { int a = 0; for (int b2 = 0; b2 < NB; ++b2) a |= reds[b2]; anyred = a; }
    __syncthreads();

    // ================= PHASE A =================
    if (anyred) {  // tree U-matmul partials: 32 cols x 128 b x 256 K per WG
      float acc[4][4];
      #pragma unroll
      for (int i = 0; i < 4; ++i)
        #pragma unroll
        for (int j = 0; j < 4; ++j) acc[i][j] = 0.0f;

      const int cg_ = t >> 5;          // col group 0..7 (4 cols)
      const int bg  = t & 31;          // b group 0..31 (4 b)
      const int srw = t >> 1, sseg = t & 1;
      float4 pre[4];

      auto ldchunk = [&](int ch) {
        int sp = (ks < 2) ? sp1s[srw] : sp2s[srw];
        const float* src = p.stack + (size_t)(srw * SROWS + sp) * D2
                           + ((ks & 1) * 256 + ch * 32 + sseg * 16);
        pre[0] = ((const float4*)src)[0];
        pre[1] = ((const float4*)src)[1];
        pre[2] = ((const float4*)src)[2];
        pre[3] = ((const float4*)src)[3];
      };
      ldchunk(0);
      for (int ch = 0; ch < 8; ++ch) {
        __syncthreads();
        float* dst = &scratch[srw][sseg * 16];
        ((float4*)dst)[0] = pre[0]; ((float4*)dst)[1] = pre[1];
        ((float4*)dst)[2] = pre[2]; ((float4*)dst)[3] = pre[3];
        __syncthreads();
        if (ch + 1 < 8) ldchunk(ch + 1);   // prefetch next chunk into regs
        #pragma unroll
        for (int k4 = 0; k4 < 32; k4 += 4) {
          float4 wv[4], ov[4];
          #pragma unroll
          for (int i = 0; i < 4; ++i) wv[i] = *(const float4*)&wTree[cg_ * 4 + i][ch * 32 + k4];
          #pragma unroll
          for (int j = 0; j < 4; ++j) ov[j] = *(const float4*)&scratch[bg * 4 + j][k4];
          #pragma unroll
          for (int i = 0; i < 4; ++i)
            #pragma unroll
            for (int j = 0; j < 4; ++j)
              acc[i][j] += wv[i].x * ov[j].x + wv[i].y * ov[j].y
                         + wv[i].z * ov[j].z + wv[i].w * ov[j].w;
        }
      }
      float* hp = p.hpre4 + (size_t)ks * NB * 2048;
      #pragma unroll
      for (int i = 0; i < 4; ++i) {
        int cabs = g * 512 + n0 + cg_ * 4 + i;
        #pragma unroll
        for (int j = 0; j < 4; ++j) {
          int b = bg * 4 + j;
          hp[(size_t)b * 2048 + cabs] = acc[i][j];
        }
      }
    }

    // ---- tracking matmul (every step): tile 16b x 8c, K=1600
    {
      float (*tin)[132] = (float (*)[132]) & scratch[0][0];
      const int kshalf = t >> 7;
      const int cl = (t >> 4) & 7;
      const int bl = t & 15;
      const int strow = t >> 4;   // 0..15
      const int stseg = t & 15;   // 0..15
      float tacc = 0.0f;
      for (int ch = 0; ch < 13; ++ch) {
        __syncthreads();
        int b_abs = tb * 16 + strow;
        if (ch < 12) {
          int reg = ch >> 2;              // 0:buf_h 1:sp1_h 2:sp2_h
          int kloc = (ch & 3) * 128 + stseg * 8;
          float4 v0, v1;
          if (reg == 0) {
            int bi = bufs[b_abs];
            if (bi < LL) {
              const float* s2_ = p.seq + (size_t)(b_abs * LL + bi) * D2 + kloc;
              v0 = ((const float4*)s2_)[0]; v1 = ((const float4*)s2_)[1];
            } else { v0 = make_float4(0.f,0.f,0.f,0.f); v1 = v0; }
          } else {
            int sp = (reg == 1) ? sp1s[b_abs] : sp2s[b_abs];
            const float* s2_ = p.stack + (size_t)(b_abs * SROWS + sp) * D2 + kloc;
            v0 = ((const float4*)s2_)[0]; v1 = ((const float4*)s2_)[1];
          }
          *(float4*)&tin[strow][stseg * 8]     = v0;
          *(float4*)&tin[strow][stseg * 8 + 4] = v1;
        } else {
          const float* s2_ = p.thb[cur] + (size_t)b_abs * 64 + stseg * 4;
          *(float4*)&tin[strow][stseg * 4] = *(const float4*)s2_;
        }
        __syncthreads();
        int half = (ch < 12) ? 64 : 32;
        int kbase = kshalf * half;
        for (int kq = 0; kq < half; kq += 4) {
          float4 wv  = *(const float4*)&wTrack[cl][ch * 128 + kbase + kq];
          float4 ovv = *(const float4*)&tin[bl][kbase + kq];
          tacc += wv.x * ovv.x + wv.y * ovv.y + wv.z * ovv.z + wv.w * ovv.w;
        }
      }
      __syncthreads();
      if (kshalf == 1) tpart[cl * 16 + bl] = tacc;
      __syncthreads();
      if (kshalf == 0) {
        float s = tacc + tpart[cl * 16 + bl];
        p.tg[(size_t)(tb * 16 + bl) * 256 + tcid * 8 + cl] = s;
      }
    }

    gsync(p.cnt, p.bar, ++gen);

    // ================= PHASE B =================
    {
      float (*th2s)[68] = (float (*)[68]) & scratch[0][0];
      // B.1 tracking LSTM elementwise for this WG's b-half (redundant per WG)
      {
        const int jset = t & 3, b_l = t >> 2;
        const int b = b0B + b_l;
        const int j0 = jset * 16;
        const float* tgrow = p.tg + (size_t)b * 256;
        const float* tcrow = p.tcb[cur] + (size_t)b * 64;
        float4 vi[4], vf[4], vg[4], vo[4], vc[4];
        #pragma unroll
        for (int q = 0; q < 4; ++q) {
          vi[q] = *(const float4*)(tgrow + j0 + 4 * q);
          vf[q] = *(const float4*)(tgrow + 64 + j0 + 4 * q);
          vg[q] = *(const float4*)(tgrow + 128 + j0 + 4 * q);
          vo[q] = *(const float4*)(tgrow + 192 + j0 + 4 * q);
          vc[q] = *(const float4*)(tcrow + j0 + 4 * q);
        }
        const bool wrt = ((w & 127) == 0);   // w==0 and w==128 persist th/tc
        float* thn = p.thb[nxt] + (size_t)b * 64;
        float* tcn = p.tcb[nxt] + (size_t)b * 64;
        #pragma unroll
        for (int q = 0; q < 4; ++q) {
          #pragma unroll
          for (int e = 0; e < 4; ++e) {
            int j = j0 + 4 * q + e;
            float gi = ((const float*)&vi[q])[e] + p.tbih[j]       + p.tbhh[j];
            float gf = ((const float*)&vf[q])[e] + p.tbih[64 + j]  + p.tbhh[64 + j];
            float gg = ((const float*)&vg[q])[e] + p.tbih[128 + j] + p.tbhh[128 + j];
            float go = ((const float*)&vo[q])[e] + p.tbih[192 + j] + p.tbhh[192 + j];
            float c2 = sigm(gf) * ((const float*)&vc[q])[e] + sigm(gi) * tanhf(gg);
            float h2 = sigm(go) * tanhf(c2);
            th2s[b_l][j] = h2;
            if (wrt) { thn[j] = h2; tcn[j] = c2; }
          }
        }
      }
      __syncthreads();
      // B.2 tree-cell elementwise + stack row write (+ final output)
      {
        const int n_i = t & 3, b_l = t >> 2;
        const int n = n0B + n_i, b = b0B + b_l;
        const int rd = reds[b];
        float hval, cval;
        if (anyred && rd) {
          float pr[4];
          #pragma unroll
          for (int g2 = 0; g2 < 4; ++g2) {
            size_t base = (size_t)b * 2048 + g2 * 512 + n;
            pr[g2] = p.hpre4[base]
                   + p.hpre4[base + (size_t)NB * 2048]
                   + p.hpre4[base + (size_t)2 * NB * 2048]
                   + p.hpre4[base + (size_t)3 * NB * 2048];
          }
          #pragma unroll
          for (int j4 = 0; j4 < 64; j4 += 4) {
            float4 xv = *(const float4*)&th2s[b_l][j4];
            #pragma unroll
            for (int g2 = 0; g2 < 4; ++g2) {
              float4 wv = *(const float4*)&wXs[g2][n_i][j4];
              pr[g2] += xv.x * wv.x + xv.y * wv.y + xv.z * wv.z + xv.w * wv.w;
            }
          }
          float iv  = sigm(pr[0] + biasS[0][n_i]);
          float ov_ = sigm(pr[1] + biasS[1][n_i]);
          float fv  = sigm(pr[2] + biasS[2][n_i]);
          float uv  = tanhf(pr[3] + biasS[3][n_i]);
          float cl_ = p.stack[(size_t)(b * SROWS + sp1s[b]) * D2 + 512 + n];
          float cr_ = p.stack[(size_t)(b * SROWS + sp2s[b]) * D2 + 512 + n];
          cval = iv * uv + fv * (cl_ + cr_);
          hval = ov_ * tanhf(cval);
        } else {
          int bi = bufs[b];
          if (bi < LL) {
            const float* s2_ = p.seq + (size_t)(b * LL + bi) * D2;
            hval = s2_[n]; cval = s2_[512 + n];
          } else { hval = 0.0f; cval = 0.0f; }
        }
        float* srow_ = p.stack + (size_t)(b * SROWS + step) * D2;
        srow_[n] = hval;
        srow_[512 + n] = cval;
        if (step == TT) p.out[(size_t)b * HH + n] = hval;
      }
    }
    gsync(p.cnt, p.bar, ++gen);
  }
}

extern "C" void kernel_launch(void* const* d_in, const int* in_sizes, int n_in,
                              void* d_out, int out_size, void* d_ws, size_t ws_size,
                              hipStream_t stream) {
  Params p;
  p.seq   = (const float*)d_in[0];
  p.trans = (const int*)d_in[1];
  p.Wx[0] = (const float*)d_in[2];   // W_i
  p.Wx[1] = (const float*)d_in[4];   // W_o
  p.Wx[2] = (const float*)d_in[4];   // W_o  (ref bug: f-gate uses W_o)
  p.Wx[3] = (const float*)d_in[5];   // W_u
  p.Ul[0] = (const float*)d_in[6];  p.Ur[0] = (const float*)d_in[7];    // i
  p.Ul[1] = (const float*)d_in[10]; p.Ur[1] = (const float*)d_in[11];   // o
  p.Ul[2] = (const float*)d_in[8];  p.Ur[2] = (const float*)d_in[9];    // f
  p.Ul[3] = (const float*)d_in[12]; p.Ur[3] = (const float*)d_in[13];   // u
  p.bias[0] = (const float*)d_in[14];  // b_i
  p.bias[1] = (const float*)d_in[16];  // b_o
  p.bias[2] = (const float*)d_in[15];  // b_f
  p.bias[3] = (const float*)d_in[17];  // b_u
  p.tWih = (const float*)d_in[18];
  p.tWhh = (const float*)d_in[19];
  p.tbih = (const float*)d_in[20];
  p.tbhh = (const float*)d_in[21];
  p.th0  = (const float*)d_in[22];
  p.tc0  = (const float*)d_in[23];

  float* ws = (float*)d_ws;
  size_t off = 0;
  p.stack  = ws + off; off += (size_t)NB * SROWS * D2;   // 8,388,608 f32
  p.hpre4  = ws + off; off += (size_t)4 * NB * 2048;     // 1,048,576
  p.tg     = ws + off; off += (size_t)NB * 256;          // 32,768
  p.thb[0] = ws + off; off += NB * XD;
  p.thb[1] = ws + off; off += NB * XD;
  p.tcb[0] = ws + off; off += NB * XD;
  p.tcb[1] = ws + off; off += NB * XD;
  unsigned* barmem = (unsigned*)(ws + off); off += 16;
  if (off * sizeof(float) > ws_size) return;  // insufficient scratch; bail visibly
  p.cnt = barmem;
  p.bar = barmem + 1;
  p.out = (float*)d_out;

  // barrier state must be zeroed every call (ws poisoned once, never restored)
  hipMemsetAsync(barmem, 0, 2 * sizeof(unsigned), stream);

  void* args[] = { &p };
  hipError_t e = hipLaunchCooperativeKernel((void*)spinn_kernel, dim3(NWG), dim3(NTH),
                                            args, 0, stream);
  if (e != hipSuccess) {
    // fallback: plain launch. 256 WGs x 117KB LDS = 1 WG/CU on 256 CUs,
    // co-residency holds in practice; barrier is our own (no cg dependency).
    (void)hipGetLastError();
    spinn_kernel<<<dim3(NWG), dim3(NTH), 0, stream>>>(p);
  }
}